// Round 1
// baseline (82284.875 us; speedup 1.0000x reference)
//
#include <hip/hip_runtime.h>

// LSTM_54537494725306: 2-layer LSTM, T=2048, D=512, H=2048, OUT=64, fp32.
// Persistent cooperative kernel, 256 WGs x 512 threads (1 WG/CU, 8 waves/CU).
// Pipelined schedule: phase p computes layer1 step p, layer2 step p-1, y step p-2
// => ONE grid barrier per phase (T+2 phases total).
// Each wave owns one hidden unit per layer (4 gate rows); c1/c2 live in registers.
// h1/h2 double-buffered in ws; weights read fp32 from global (L3-resident, 218 MB).

#define T_STEPS 2048
#define DIM_D   512
#define DIM_H   2048
#define DIM_OUT 64
#define NWG     256
#define NTHR    512

// ws layout: [0,2048): barrier ints; @4096: h1buf[2][2048] f32; then h2buf[2][2048] f32.

__device__ __forceinline__ float sigf(float x)  { return 1.0f / (1.0f + __expf(-x)); }
__device__ __forceinline__ float tanh_f(float x) { return 1.0f - 2.0f / (__expf(2.0f * x) + 1.0f); }

__device__ __forceinline__ float wave_reduce(float v) {
#pragma unroll
    for (int off = 32; off > 0; off >>= 1) v += __shfl_xor(v, off, 64);
    return v;
}

// Two-level sense-free barrier: 8 group counters (stride 32 ints = 128B lines),
// root counter at bar[256], generation at bar[288]. Generation only grows.
__device__ __forceinline__ void grid_barrier(int* bar, int wg, int* sGen) {
    __syncthreads();
    if (threadIdx.x == 0) {
        const int g = *sGen;
        const int grp = wg >> 5;  // 8 groups of 32
        int a = __hip_atomic_fetch_add(&bar[grp * 32], 1, __ATOMIC_ACQ_REL, __HIP_MEMORY_SCOPE_AGENT);
        if (a == 31) {
            int r = __hip_atomic_fetch_add(&bar[256], 1, __ATOMIC_ACQ_REL, __HIP_MEMORY_SCOPE_AGENT);
            if (r == 7) {  // last WG of all 256: reset counters, publish new generation
#pragma unroll
                for (int i = 0; i < 8; ++i)
                    __hip_atomic_store(&bar[i * 32], 0, __ATOMIC_RELAXED, __HIP_MEMORY_SCOPE_AGENT);
                __hip_atomic_store(&bar[256], 0, __ATOMIC_RELAXED, __HIP_MEMORY_SCOPE_AGENT);
                __hip_atomic_store(&bar[288], g + 1, __ATOMIC_RELEASE, __HIP_MEMORY_SCOPE_AGENT);
            }
        }
        while (__hip_atomic_load(&bar[288], __ATOMIC_RELAXED, __HIP_MEMORY_SCOPE_AGENT) <= g) {
            __builtin_amdgcn_s_sleep(2);
        }
        __builtin_amdgcn_fence(__ATOMIC_ACQUIRE, "agent");
        *sGen = g + 1;
    }
    __syncthreads();
}

__global__ void lstm_init(int* bar, float* h1buf, float* h2buf) {
    int i = threadIdx.x + blockIdx.x * blockDim.x;
    if (i < 512) bar[i] = 0;
    if (i < 2 * DIM_H) { h1buf[i] = 0.0f; h2buf[i] = 0.0f; }
}

__global__ __launch_bounds__(NTHR, 2) void lstm_persist(
    const float* __restrict__ x,
    const float* __restrict__ Wih1, const float* __restrict__ Whh1,
    const float* __restrict__ bih1, const float* __restrict__ bhh1,
    const float* __restrict__ Wih2, const float* __restrict__ Whh2,
    const float* __restrict__ bih2, const float* __restrict__ bhh2,
    const float* __restrict__ Wlin, const float* __restrict__ blin,
    float* __restrict__ out,
    int* bar, float* h1buf, float* h2buf)
{
    const int wg   = blockIdx.x;
    const int wave = threadIdx.x >> 6;
    const int lane = threadIdx.x & 63;
    const int unit = wg * 8 + wave;   // hidden unit owned by this wave (both layers)

    __shared__ int sGen;
    if (threadIdx.x == 0) sGen = 0;

    const int r0 = unit, r1 = DIM_H + unit, r2 = 2 * DIM_H + unit, r3 = 3 * DIM_H + unit;
    const float b1_0 = bih1[r0] + bhh1[r0];
    const float b1_1 = bih1[r1] + bhh1[r1];
    const float b1_2 = bih1[r2] + bhh1[r2];
    const float b1_3 = bih1[r3] + bhh1[r3];
    const float b2_0 = bih2[r0] + bhh2[r0];
    const float b2_1 = bih2[r1] + bhh2[r1];
    const float b2_2 = bih2[r2] + bhh2[r2];
    const float b2_3 = bih2[r3] + bhh2[r3];

    const float4* wi1_0 = (const float4*)(Wih1 + (size_t)r0 * DIM_D);
    const float4* wi1_1 = (const float4*)(Wih1 + (size_t)r1 * DIM_D);
    const float4* wi1_2 = (const float4*)(Wih1 + (size_t)r2 * DIM_D);
    const float4* wi1_3 = (const float4*)(Wih1 + (size_t)r3 * DIM_D);
    const float4* wh1_0 = (const float4*)(Whh1 + (size_t)r0 * DIM_H);
    const float4* wh1_1 = (const float4*)(Whh1 + (size_t)r1 * DIM_H);
    const float4* wh1_2 = (const float4*)(Whh1 + (size_t)r2 * DIM_H);
    const float4* wh1_3 = (const float4*)(Whh1 + (size_t)r3 * DIM_H);
    const float4* wi2_0 = (const float4*)(Wih2 + (size_t)r0 * DIM_H);
    const float4* wi2_1 = (const float4*)(Wih2 + (size_t)r1 * DIM_H);
    const float4* wi2_2 = (const float4*)(Wih2 + (size_t)r2 * DIM_H);
    const float4* wi2_3 = (const float4*)(Wih2 + (size_t)r3 * DIM_H);
    const float4* wh2_0 = (const float4*)(Whh2 + (size_t)r0 * DIM_H);
    const float4* wh2_1 = (const float4*)(Whh2 + (size_t)r1 * DIM_H);
    const float4* wh2_2 = (const float4*)(Whh2 + (size_t)r2 * DIM_H);
    const float4* wh2_3 = (const float4*)(Whh2 + (size_t)r3 * DIM_H);

    const bool  do_y = (wg < DIM_OUT) && (wave == 0);
    const float by   = (wg < DIM_OUT) ? blin[wg] : 0.0f;
    const float4* wy = (const float4*)(Wlin + (size_t)(wg < DIM_OUT ? wg : 0) * DIM_H);

    float c1 = 0.0f, c2 = 0.0f;

    for (int p = 0; p < T_STEPS + 2; ++p) {
        const float* h1_prev  = h1buf + (size_t)((p + 1) & 1) * DIM_H;  // h1[p-1]
        float*       h1_cur   = h1buf + (size_t)(p & 1) * DIM_H;        // h1[p]
        const float* h2_prev2 = h2buf + (size_t)(p & 1) * DIM_H;        // h2[p-2]
        float*       h2_cur   = h2buf + (size_t)((p + 1) & 1) * DIM_H;  // h2[p-1]

        // ---------------- layer 1, step p ----------------
        if (p < T_STEPS) {
            float a0 = 0.f, a1 = 0.f, a2 = 0.f, a3 = 0.f;
            const float4* xt = (const float4*)(x + (size_t)p * DIM_D);
#pragma unroll
            for (int i = 0; i < DIM_D / 256; ++i) {
                const int idx = lane + 64 * i;
                const float4 v  = xt[idx];
                const float4 w0 = wi1_0[idx], w1 = wi1_1[idx], w2 = wi1_2[idx], w3 = wi1_3[idx];
                a0 = fmaf(v.x, w0.x, fmaf(v.y, w0.y, fmaf(v.z, w0.z, fmaf(v.w, w0.w, a0))));
                a1 = fmaf(v.x, w1.x, fmaf(v.y, w1.y, fmaf(v.z, w1.z, fmaf(v.w, w1.w, a1))));
                a2 = fmaf(v.x, w2.x, fmaf(v.y, w2.y, fmaf(v.z, w2.z, fmaf(v.w, w2.w, a2))));
                a3 = fmaf(v.x, w3.x, fmaf(v.y, w3.y, fmaf(v.z, w3.z, fmaf(v.w, w3.w, a3))));
            }
            const float4* hp = (const float4*)h1_prev;
#pragma unroll
            for (int i = 0; i < DIM_H / 256; ++i) {
                const int idx = lane + 64 * i;
                const float4 v  = hp[idx];
                const float4 w0 = wh1_0[idx], w1 = wh1_1[idx], w2 = wh1_2[idx], w3 = wh1_3[idx];
                a0 = fmaf(v.x, w0.x, fmaf(v.y, w0.y, fmaf(v.z, w0.z, fmaf(v.w, w0.w, a0))));
                a1 = fmaf(v.x, w1.x, fmaf(v.y, w1.y, fmaf(v.z, w1.z, fmaf(v.w, w1.w, a1))));
                a2 = fmaf(v.x, w2.x, fmaf(v.y, w2.y, fmaf(v.z, w2.z, fmaf(v.w, w2.w, a2))));
                a3 = fmaf(v.x, w3.x, fmaf(v.y, w3.y, fmaf(v.z, w3.z, fmaf(v.w, w3.w, a3))));
            }
            a0 = wave_reduce(a0); a1 = wave_reduce(a1);
            a2 = wave_reduce(a2); a3 = wave_reduce(a3);
            const float gi = sigf(a0 + b1_0);
            const float gf = sigf(a1 + b1_1);
            const float gg = tanh_f(a2 + b1_2);
            const float go = sigf(a3 + b1_3);
            c1 = fmaf(gf, c1, gi * gg);
            const float hv = go * tanh_f(c1);
            if (lane == 0) h1_cur[unit] = hv;
        }

        // ---------------- layer 2, step p-1 ----------------
        if (p >= 1 && p <= T_STEPS) {
            float a0 = 0.f, a1 = 0.f, a2 = 0.f, a3 = 0.f;
            const float4* hp = (const float4*)h1_prev;   // h1[p-1]
#pragma unroll
            for (int i = 0; i < DIM_H / 256; ++i) {
                const int idx = lane + 64 * i;
                const float4 v  = hp[idx];
                const float4 w0 = wi2_0[idx], w1 = wi2_1[idx], w2 = wi2_2[idx], w3 = wi2_3[idx];
                a0 = fmaf(v.x, w0.x, fmaf(v.y, w0.y, fmaf(v.z, w0.z, fmaf(v.w, w0.w, a0))));
                a1 = fmaf(v.x, w1.x, fmaf(v.y, w1.y, fmaf(v.z, w1.z, fmaf(v.w, w1.w, a1))));
                a2 = fmaf(v.x, w2.x, fmaf(v.y, w2.y, fmaf(v.z, w2.z, fmaf(v.w, w2.w, a2))));
                a3 = fmaf(v.x, w3.x, fmaf(v.y, w3.y, fmaf(v.z, w3.z, fmaf(v.w, w3.w, a3))));
            }
            const float4* hq = (const float4*)h2_prev2;  // h2[p-2]
#pragma unroll
            for (int i = 0; i < DIM_H / 256; ++i) {
                const int idx = lane + 64 * i;
                const float4 v  = hq[idx];
                const float4 w0 = wh2_0[idx], w1 = wh2_1[idx], w2 = wh2_2[idx], w3 = wh2_3[idx];
                a0 = fmaf(v.x, w0.x, fmaf(v.y, w0.y, fmaf(v.z, w0.z, fmaf(v.w, w0.w, a0))));
                a1 = fmaf(v.x, w1.x, fmaf(v.y, w1.y, fmaf(v.z, w1.z, fmaf(v.w, w1.w, a1))));
                a2 = fmaf(v.x, w2.x, fmaf(v.y, w2.y, fmaf(v.z, w2.z, fmaf(v.w, w2.w, a2))));
                a3 = fmaf(v.x, w3.x, fmaf(v.y, w3.y, fmaf(v.z, w3.z, fmaf(v.w, w3.w, a3))));
            }
            a0 = wave_reduce(a0); a1 = wave_reduce(a1);
            a2 = wave_reduce(a2); a3 = wave_reduce(a3);
            const float gi = sigf(a0 + b2_0);
            const float gf = sigf(a1 + b2_1);
            const float gg = tanh_f(a2 + b2_2);
            const float go = sigf(a3 + b2_3);
            c2 = fmaf(gf, c2, gi * gg);
            const float hv = go * tanh_f(c2);
            if (lane == 0) h2_cur[unit] = hv;
        }

        // ---------------- y, step p-2 ----------------
        if (do_y && p >= 2) {
            float a = 0.f;
            const float4* hq = (const float4*)h2_prev2;  // h2[p-2], stable this phase
#pragma unroll
            for (int i = 0; i < DIM_H / 256; ++i) {
                const int idx = lane + 64 * i;
                const float4 v = hq[idx];
                const float4 w = wy[idx];
                a = fmaf(v.x, w.x, fmaf(v.y, w.y, fmaf(v.z, w.z, fmaf(v.w, w.w, a))));
            }
            a = wave_reduce(a);
            if (lane == 0) out[(size_t)(p - 2) * DIM_OUT + wg] = a + by;
        }

        grid_barrier(bar, wg, &sGen);
    }
}

extern "C" void kernel_launch(void* const* d_in, const int* in_sizes, int n_in,
                              void* d_out, int out_size, void* d_ws, size_t ws_size,
                              hipStream_t stream) {
    const float* x    = (const float*)d_in[0];
    const float* Wih1 = (const float*)d_in[1];
    const float* Whh1 = (const float*)d_in[2];
    const float* bih1 = (const float*)d_in[3];
    const float* bhh1 = (const float*)d_in[4];
    const float* Wih2 = (const float*)d_in[5];
    const float* Whh2 = (const float*)d_in[6];
    const float* bih2 = (const float*)d_in[7];
    const float* bhh2 = (const float*)d_in[8];
    const float* Wlin = (const float*)d_in[9];
    const float* blin = (const float*)d_in[10];
    float* out = (float*)d_out;

    int*   bar   = (int*)d_ws;
    float* h1buf = (float*)((char*)d_ws + 4096);
    float* h2buf = h1buf + 2 * DIM_H;

    lstm_init<<<16, 256, 0, stream>>>(bar, h1buf, h2buf);

    void* args[] = {
        (void*)&x,
        (void*)&Wih1, (void*)&Whh1, (void*)&bih1, (void*)&bhh1,
        (void*)&Wih2, (void*)&Whh2, (void*)&bih2, (void*)&bhh2,
        (void*)&Wlin, (void*)&blin,
        (void*)&out, (void*)&bar, (void*)&h1buf, (void*)&h2buf
    };
    hipLaunchCooperativeKernel((const void*)lstm_persist, dim3(NWG), dim3(NTHR),
                               args, 0, stream);
}

// Round 2
// 55969.543 us; speedup vs baseline: 1.4702x; 1.4702x over previous
//
#include <hip/hip_runtime.h>
#include <hip/hip_fp16.h>

// LSTM_54537494725306: 2-layer LSTM, T=2048, D=512, H=2048, OUT=64, fp32 in/out.
// R2: weights converted to fp16 in workspace each call (104.3 MB working set ->
// Infinity-Cache resident; R1's fp32 weights thrashed L3 and streamed 107 MB/step
// from HBM at ~2.1 TB/s). Persistent cooperative kernel, 256 WGs x 512 threads,
// 1 grid barrier per timestep, c1/c2 in registers, h double-buffered in ws.

#define T_STEPS 2048
#define DIM_D   512
#define DIM_H   2048
#define DIM_OUT 64
#define NWG     256
#define NTHR    512

#define N_WIH1 (4 * DIM_H * DIM_D)   //  4,194,304
#define N_WHH1 (4 * DIM_H * DIM_H)   // 16,777,216
#define N_WIH2 (4 * DIM_H * DIM_H)
#define N_WHH2 (4 * DIM_H * DIM_H)
#define N_WLIN (DIM_OUT * DIM_H)     //    131,072
#define WS_WEIGHT_OFF 65536

__device__ __forceinline__ float sigf(float x)   { return 1.0f / (1.0f + __expf(-x)); }
__device__ __forceinline__ float tanh_f(float x) { return 1.0f - 2.0f / (__expf(2.0f * x) + 1.0f); }

__device__ __forceinline__ float wave_reduce(float v) {
#pragma unroll
    for (int off = 32; off > 0; off >>= 1) v += __shfl_xor(v, off, 64);
    return v;
}

struct F8 { float4 a, b; };

__device__ __forceinline__ F8 load8(const float* __restrict__ p, int e) {
    F8 r;
    const float4* q = (const float4*)(p + e);
    r.a = q[0]; r.b = q[1];
    return r;
}
__device__ __forceinline__ F8 load8(const __half* __restrict__ p, int e) {
    uint4 u = *(const uint4*)(p + e);
    float2 f0 = __half22float2(*(__half2*)&u.x);
    float2 f1 = __half22float2(*(__half2*)&u.y);
    float2 f2 = __half22float2(*(__half2*)&u.z);
    float2 f3 = __half22float2(*(__half2*)&u.w);
    F8 r;
    r.a = make_float4(f0.x, f0.y, f1.x, f1.y);
    r.b = make_float4(f2.x, f2.y, f3.x, f3.y);
    return r;
}

__device__ __forceinline__ float dot8(const F8& v, const F8& w, float acc) {
    acc = fmaf(v.a.x, w.a.x, acc); acc = fmaf(v.a.y, w.a.y, acc);
    acc = fmaf(v.a.z, w.a.z, acc); acc = fmaf(v.a.w, w.a.w, acc);
    acc = fmaf(v.b.x, w.b.x, acc); acc = fmaf(v.b.y, w.b.y, acc);
    acc = fmaf(v.b.z, w.b.z, acc); acc = fmaf(v.b.w, w.b.w, acc);
    return acc;
}

// 4-row dot over K elements: lane-strided 8-element chunks.
template<int K, typename WT>
__device__ __forceinline__ void dot4(const float* __restrict__ v,
                                     const WT* __restrict__ w0, const WT* __restrict__ w1,
                                     const WT* __restrict__ w2, const WT* __restrict__ w3,
                                     int lane, float& a0, float& a1, float& a2, float& a3) {
#pragma unroll
    for (int i = 0; i < K / 512; ++i) {
        const int e = (lane + 64 * i) * 8;
        const F8 vv = load8(v, e);
        a0 = dot8(vv, load8(w0, e), a0);
        a1 = dot8(vv, load8(w1, e), a1);
        a2 = dot8(vv, load8(w2, e), a2);
        a3 = dot8(vv, load8(w3, e), a3);
    }
}

// Two-level sense-free barrier (proven in R1).
__device__ __forceinline__ void grid_barrier(int* bar, int wg, int* sGen) {
    __syncthreads();
    if (threadIdx.x == 0) {
        const int g = *sGen;
        const int grp = wg >> 5;
        int a = __hip_atomic_fetch_add(&bar[grp * 32], 1, __ATOMIC_ACQ_REL, __HIP_MEMORY_SCOPE_AGENT);
        if (a == 31) {
            int r = __hip_atomic_fetch_add(&bar[256], 1, __ATOMIC_ACQ_REL, __HIP_MEMORY_SCOPE_AGENT);
            if (r == 7) {
#pragma unroll
                for (int i = 0; i < 8; ++i)
                    __hip_atomic_store(&bar[i * 32], 0, __ATOMIC_RELAXED, __HIP_MEMORY_SCOPE_AGENT);
                __hip_atomic_store(&bar[256], 0, __ATOMIC_RELAXED, __HIP_MEMORY_SCOPE_AGENT);
                __hip_atomic_store(&bar[288], g + 1, __ATOMIC_RELEASE, __HIP_MEMORY_SCOPE_AGENT);
            }
        }
        while (__hip_atomic_load(&bar[288], __ATOMIC_RELAXED, __HIP_MEMORY_SCOPE_AGENT) <= g) {
            __builtin_amdgcn_s_sleep(2);
        }
        __builtin_amdgcn_fence(__ATOMIC_ACQUIRE, "agent");
        *sGen = g + 1;
    }
    __syncthreads();
}

__global__ void lstm_init(int* bar, float* h1buf, float* h2buf) {
    int i = threadIdx.x + blockIdx.x * blockDim.x;
    if (i < 512) bar[i] = 0;
    if (i < 2 * DIM_H) { h1buf[i] = 0.0f; h2buf[i] = 0.0f; }
}

// fp32 -> fp16 (RNE), 4 elements/thread. n divisible by 4 for all matrices.
__global__ void convert_f16(const float* __restrict__ src, __half* __restrict__ dst, int n4) {
    int i = threadIdx.x + blockIdx.x * blockDim.x;
    if (i < n4) {
        float4 f = ((const float4*)src)[i];
        __half2 h01 = __floats2half2_rn(f.x, f.y);
        __half2 h23 = __floats2half2_rn(f.z, f.w);
        uint2 o;
        o.x = *(unsigned int*)&h01;
        o.y = *(unsigned int*)&h23;
        ((uint2*)dst)[i] = o;
    }
}

template<typename WT>
__global__ __launch_bounds__(NTHR, 2) void lstm_persist(
    const float* __restrict__ x,
    const WT* __restrict__ Wih1, const WT* __restrict__ Whh1,
    const float* __restrict__ bih1, const float* __restrict__ bhh1,
    const WT* __restrict__ Wih2, const WT* __restrict__ Whh2,
    const float* __restrict__ bih2, const float* __restrict__ bhh2,
    const WT* __restrict__ Wlin, const float* __restrict__ blin,
    float* __restrict__ out,
    int* bar, float* h1buf, float* h2buf)
{
    const int wg   = blockIdx.x;
    const int wave = threadIdx.x >> 6;
    const int lane = threadIdx.x & 63;
    const int unit = wg * 8 + wave;

    __shared__ int sGen;
    if (threadIdx.x == 0) sGen = 0;

    const int r0 = unit, r1 = DIM_H + unit, r2 = 2 * DIM_H + unit, r3 = 3 * DIM_H + unit;
    const float b1_0 = bih1[r0] + bhh1[r0];
    const float b1_1 = bih1[r1] + bhh1[r1];
    const float b1_2 = bih1[r2] + bhh1[r2];
    const float b1_3 = bih1[r3] + bhh1[r3];
    const float b2_0 = bih2[r0] + bhh2[r0];
    const float b2_1 = bih2[r1] + bhh2[r1];
    const float b2_2 = bih2[r2] + bhh2[r2];
    const float b2_3 = bih2[r3] + bhh2[r3];

    const WT* wi1_0 = Wih1 + (size_t)r0 * DIM_D;
    const WT* wi1_1 = Wih1 + (size_t)r1 * DIM_D;
    const WT* wi1_2 = Wih1 + (size_t)r2 * DIM_D;
    const WT* wi1_3 = Wih1 + (size_t)r3 * DIM_D;
    const WT* wh1_0 = Whh1 + (size_t)r0 * DIM_H;
    const WT* wh1_1 = Whh1 + (size_t)r1 * DIM_H;
    const WT* wh1_2 = Whh1 + (size_t)r2 * DIM_H;
    const WT* wh1_3 = Whh1 + (size_t)r3 * DIM_H;
    const WT* wi2_0 = Wih2 + (size_t)r0 * DIM_H;
    const WT* wi2_1 = Wih2 + (size_t)r1 * DIM_H;
    const WT* wi2_2 = Wih2 + (size_t)r2 * DIM_H;
    const WT* wi2_3 = Wih2 + (size_t)r3 * DIM_H;
    const WT* wh2_0 = Whh2 + (size_t)r0 * DIM_H;
    const WT* wh2_1 = Whh2 + (size_t)r1 * DIM_H;
    const WT* wh2_2 = Whh2 + (size_t)r2 * DIM_H;
    const WT* wh2_3 = Whh2 + (size_t)r3 * DIM_H;

    const bool  do_y = (wg < DIM_OUT) && (wave == 0);
    const float by   = (wg < DIM_OUT) ? blin[wg] : 0.0f;
    const WT*   wy   = Wlin + (size_t)(wg < DIM_OUT ? wg : 0) * DIM_H;

    float c1 = 0.0f, c2 = 0.0f;

    for (int p = 0; p < T_STEPS + 2; ++p) {
        const float* h1_prev  = h1buf + (size_t)((p + 1) & 1) * DIM_H;  // h1[p-1]
        float*       h1_cur   = h1buf + (size_t)(p & 1) * DIM_H;        // h1[p]
        const float* h2_prev2 = h2buf + (size_t)(p & 1) * DIM_H;        // h2[p-2]
        float*       h2_cur   = h2buf + (size_t)((p + 1) & 1) * DIM_H;  // h2[p-1]

        // ---------------- layer 1, step p ----------------
        if (p < T_STEPS) {
            float a0 = 0.f, a1 = 0.f, a2 = 0.f, a3 = 0.f;
            dot4<DIM_D>(x + (size_t)p * DIM_D, wi1_0, wi1_1, wi1_2, wi1_3, lane, a0, a1, a2, a3);
            dot4<DIM_H>(h1_prev, wh1_0, wh1_1, wh1_2, wh1_3, lane, a0, a1, a2, a3);
            a0 = wave_reduce(a0); a1 = wave_reduce(a1);
            a2 = wave_reduce(a2); a3 = wave_reduce(a3);
            const float gi = sigf(a0 + b1_0);
            const float gf = sigf(a1 + b1_1);
            const float gg = tanh_f(a2 + b1_2);
            const float go = sigf(a3 + b1_3);
            c1 = fmaf(gf, c1, gi * gg);
            const float hv = go * tanh_f(c1);
            if (lane == 0) h1_cur[unit] = hv;
        }

        // ---------------- layer 2, step p-1 ----------------
        if (p >= 1 && p <= T_STEPS) {
            float a0 = 0.f, a1 = 0.f, a2 = 0.f, a3 = 0.f;
            dot4<DIM_H>(h1_prev,  wi2_0, wi2_1, wi2_2, wi2_3, lane, a0, a1, a2, a3);
            dot4<DIM_H>(h2_prev2, wh2_0, wh2_1, wh2_2, wh2_3, lane, a0, a1, a2, a3);
            a0 = wave_reduce(a0); a1 = wave_reduce(a1);
            a2 = wave_reduce(a2); a3 = wave_reduce(a3);
            const float gi = sigf(a0 + b2_0);
            const float gf = sigf(a1 + b2_1);
            const float gg = tanh_f(a2 + b2_2);
            const float go = sigf(a3 + b2_3);
            c2 = fmaf(gf, c2, gi * gg);
            const float hv = go * tanh_f(c2);
            if (lane == 0) h2_cur[unit] = hv;
        }

        // ---------------- y, step p-2 ----------------
        if (do_y && p >= 2) {
            float a = 0.f;
#pragma unroll
            for (int i = 0; i < DIM_H / 512; ++i) {
                const int e = (lane + 64 * i) * 8;
                a = dot8(load8(h2_prev2, e), load8(wy, e), a);
            }
            a = wave_reduce(a);
            if (lane == 0) out[(size_t)(p - 2) * DIM_OUT + wg] = a + by;
        }

        grid_barrier(bar, wg, &sGen);
    }
}

extern "C" void kernel_launch(void* const* d_in, const int* in_sizes, int n_in,
                              void* d_out, int out_size, void* d_ws, size_t ws_size,
                              hipStream_t stream) {
    const float* x    = (const float*)d_in[0];
    const float* Wih1 = (const float*)d_in[1];
    const float* Whh1 = (const float*)d_in[2];
    const float* bih1 = (const float*)d_in[3];
    const float* bhh1 = (const float*)d_in[4];
    const float* Wih2 = (const float*)d_in[5];
    const float* Whh2 = (const float*)d_in[6];
    const float* bih2 = (const float*)d_in[7];
    const float* bhh2 = (const float*)d_in[8];
    const float* Wlin = (const float*)d_in[9];
    const float* blin = (const float*)d_in[10];
    float* out = (float*)d_out;

    int*   bar   = (int*)d_ws;
    float* h1buf = (float*)((char*)d_ws + 4096);
    float* h2buf = h1buf + 2 * DIM_H;

    lstm_init<<<16, 256, 0, stream>>>(bar, h1buf, h2buf);

    const size_t nweights = (size_t)N_WIH1 + N_WHH1 + N_WIH2 + N_WHH2 + N_WLIN;
    const size_t need = WS_WEIGHT_OFF + sizeof(__half) * nweights;

    if (ws_size >= need) {
        __half* hWih1 = (__half*)((char*)d_ws + WS_WEIGHT_OFF);
        __half* hWhh1 = hWih1 + N_WIH1;
        __half* hWih2 = hWhh1 + N_WHH1;
        __half* hWhh2 = hWih2 + N_WIH2;
        __half* hWlin = hWhh2 + N_WHH2;

        const float* srcs[5] = { Wih1, Whh1, Wih2, Whh2, Wlin };
        __half*      dsts[5] = { hWih1, hWhh1, hWih2, hWhh2, hWlin };
        const int    ns[5]   = { N_WIH1, N_WHH1, N_WIH2, N_WHH2, N_WLIN };
        for (int m = 0; m < 5; ++m) {
            int n4 = ns[m] / 4;
            convert_f16<<<(n4 + 255) / 256, 256, 0, stream>>>(srcs[m], dsts[m], n4);
        }

        const __half* cWih1 = hWih1; const __half* cWhh1 = hWhh1;
        const __half* cWih2 = hWih2; const __half* cWhh2 = hWhh2;
        const __half* cWlin = hWlin;
        void* args[] = {
            (void*)&x,
            (void*)&cWih1, (void*)&cWhh1, (void*)&bih1, (void*)&bhh1,
            (void*)&cWih2, (void*)&cWhh2, (void*)&bih2, (void*)&bhh2,
            (void*)&cWlin, (void*)&blin,
            (void*)&out, (void*)&bar, (void*)&h1buf, (void*)&h2buf
        };
        hipLaunchCooperativeKernel((const void*)lstm_persist<__half>, dim3(NWG), dim3(NTHR),
                                   args, 0, stream);
    } else {
        // Fallback: fp32 weights straight from inputs (R1 behavior).
        void* args[] = {
            (void*)&x,
            (void*)&Wih1, (void*)&Whh1, (void*)&bih1, (void*)&bhh1,
            (void*)&Wih2, (void*)&Whh2, (void*)&bih2, (void*)&bhh2,
            (void*)&Wlin, (void*)&blin,
            (void*)&out, (void*)&bar, (void*)&h1buf, (void*)&h2buf
        };
        hipLaunchCooperativeKernel((const void*)lstm_persist<float>, dim3(NWG), dim3(NTHR),
                                   args, 0, stream);
    }
}